// Round 3
// baseline (581.001 us; speedup 1.0000x reference)
//
#include <hip/hip_runtime.h>

// ECGNNEdgePredictor: 512 graphs x 30 nodes, HID=64, 5 NNConv layers + MLP head.
// One block per graph, 512 threads = 8 waves (R2: was 4 — occupancy 8->16 waves/CU).
// msg GEMM fused as P @ W2' with P[e,k*64+h] = z[e,k]*h_src[e,h] (+ones col for b2);
// z-scale (fp32) folded into the accumulator. fp16 MFMA with A-operand hi/lo split
// (2-product) -> h enters GEMMs at ~fp32 precision; fp32 master h + fp32 epilogue.

typedef float f32x4 __attribute__((ext_vector_type(4)));
typedef _Float16 f16x8 __attribute__((ext_vector_type(8)));

#define MFMA16(a, b, c) __builtin_amdgcn_mfma_f32_16x16x32_f16((a), (b), (c), 0, 0, 0)

// ws layout (bytes)
#define WS_W2S 0u        // 5*66*64*32 f16 = 1351680 B (W2 + b2 fused, B-frag order)
#define WS_W1S 1351680u  // 5*4*32*32  f16 = 40960 B
#define WS_WRS 1392640u  // 5*2*64*32  f16 = 40960 B
#define WS_BNS 1433600u  // 320 f32 scale
#define WS_BNH 1434880u  // 320 f32 shift
// total 1436160 B

__device__ inline f16x8 ld_frag_g(const _Float16* p) {
  union { uint4 u; f16x8 f; } c;
  c.u = *(const uint4*)p;
  return c.f;
}
__device__ inline f16x8 ld_frag_s(const _Float16* p) { return *(const f16x8*)p; }

// ---------------- prep: repack weights to f16 in MFMA B-fragment order ----------------
// B-frag layout per 16x16x32 k-step t: elem(t, n, q, i) = B[j = t*32 + q*8 + i][n],
// stored contiguous in (q,i) so lane (col n, q=lane>>4) loads 16B.
__global__ __launch_bounds__(256) void prep_kernel(
    const float* __restrict__ W1, const float* __restrict__ W2,
    const float* __restrict__ b2, const float* __restrict__ Wr,
    const float* __restrict__ gamma, const float* __restrict__ beta,
    const float* __restrict__ rmean, const float* __restrict__ rvar,
    unsigned char* __restrict__ ws) {
  int idx = blockIdx.x * 256 + threadIdx.x;
  _Float16* W2s = (_Float16*)(ws + WS_W2S);
  _Float16* W1s = (_Float16*)(ws + WS_W1S);
  _Float16* Wrs = (_Float16*)(ws + WS_WRS);
  float* bns = (float*)(ws + WS_BNS);
  float* bnh = (float*)(ws + WS_BNH);

  if (idx < 675840) {            // W2s: K = 2112 = 32*64 (z x h outer) + 64 (b2 rows)
    int l = idx / 135168, r = idx % 135168;
    int t = r / 2048, r2 = r % 2048;
    int n = r2 >> 5, s = r2 & 31;
    int j = t * 32 + s;
    float v = (j < 2048) ? W2[(l * 32 + (j >> 6)) * 4096 + (j & 63) * 64 + n]
                         : b2[l * 4096 + (j - 2048) * 64 + n];
    W2s[idx] = (_Float16)v;
  } else if (idx < 696320) {     // W1s: K = 128
    int i2 = idx - 675840;
    int l = i2 / 4096, r = i2 % 4096;
    int t = r >> 10, n = (r >> 5) & 31, s = r & 31;
    int j = t * 32 + s;
    W1s[i2] = (_Float16)W1[l * 4096 + j * 32 + n];
  } else if (idx < 716800) {     // Wrs: K = 64
    int i3 = idx - 696320;
    int l = i3 / 4096, r = i3 % 4096;
    int t = r >> 11, rem = r & 2047;
    int n = rem >> 5, s = rem & 31;
    int j = t * 32 + s;
    Wrs[i3] = (_Float16)Wr[l * 4096 + j * 64 + n];
  } else if (idx < 717120) {     // BN folded: scale, shift
    int i4 = idx - 716800;       // l*64 + c
    float sc = gamma[i4] * rsqrtf(rvar[i4] + 1e-5f);
    bns[i4] = sc;
    bnh[i4] = beta[i4] - rmean[i4] * sc;
  }
}

// ---------------- main: one block per graph, 512 threads = 8 waves ----------------
__global__ __launch_bounds__(512, 4) void gnn_kernel(
    const float* __restrict__ x, const int* __restrict__ bu, const int* __restrict__ bv,
    const float* __restrict__ Wp, const float* __restrict__ bp,
    const float* __restrict__ b1, const float* __restrict__ brr,
    const float* __restrict__ Wm1, const float* __restrict__ bm1,
    const float* __restrict__ Wm2, const float* __restrict__ bm2,
    const _Float16* __restrict__ W2s, const _Float16* __restrict__ W1s,
    const _Float16* __restrict__ Wrs,
    const float* __restrict__ bns, const float* __restrict__ bnh,
    float* __restrict__ out) {
  __shared__ __align__(16) float hF[32][68];         // fp32 master h
  __shared__ __align__(16) _Float16 hH[32][72];      // f16 hi part of h
  __shared__ __align__(16) _Float16 hL[32][72];      // f16 lo part (h - hi)
  __shared__ __align__(16) float zT[33][100];        // z transposed [c][e]; row 32 = ones
  __shared__ __align__(16) float agg[32][68];        // scatter accumulator
  __shared__ int srcn[96], dstn[96];
  __shared__ float invdeg[32];

  const int tid = threadIdx.x;
  const int g = blockIdx.x;
  const int wv = tid >> 6;     // 0..7
  const int ln = tid & 63;
  const int q = ln >> 4;
  const int m16 = ln & 15;

  // ---- init: edge lists (both directions), ones-column, pad rows
  if (tid < 96) {
    int s, d;
    if (tid < 41)      { s = bu[tid];      d = bv[tid]; }
    else if (tid < 82) { s = bv[tid - 41]; d = bu[tid - 41]; }
    else               { s = 0;            d = 0; }
    srcn[tid] = s; dstn[tid] = d;
    zT[32][tid] = (tid < 82) ? 1.0f : 0.0f;
  }
  if (tid < 136) { hF[30 + tid / 68][tid % 68] = 0.f; }
  if (tid < 144) {
    hH[30 + tid / 72][tid % 72] = (_Float16)0.f;
    hL[30 + tid / 72][tid % 72] = (_Float16)0.f;
  }
  __syncthreads();
  if (tid < 32) {
    int cnt = 0;
    for (int e = 0; e < 82; ++e) cnt += (dstn[e] == tid) ? 1 : 0;
    invdeg[tid] = 1.0f / (float)(cnt > 0 ? cnt : 1);
  }
  // ---- projection h0 = x @ Wp + bp (fp32, then split hi/lo)
  for (int u = tid; u < 30 * 64; u += 512) {
    int n = u >> 6, c = u & 63;
    float acc = bp[c];
#pragma unroll
    for (int k = 0; k < 8; ++k) acc += x[(g * 30 + n) * 8 + k] * Wp[k * 64 + c];
    hF[n][c] = acc;
    _Float16 hi = (_Float16)acc;
    hH[n][c] = hi;
    hL[n][c] = (_Float16)(acc - (float)hi);
  }
  __syncthreads();

  const f32x4 zero4 = {0.f, 0.f, 0.f, 0.f};

  for (int l = 0; l < 5; ++l) {
    // zero scatter buffer (atomics start only after the post-z barrier)
    for (int u = tid; u < 32 * 68; u += 512) ((float*)agg)[u] = 0.f;

    // ---- z = relu([h_src|h_dst] @ W1 + b1): M=96 N=32 K=128 -> zT[c][e] (fp32)
    // 12 tiles (6 mt x 2 nt) over 8 waves: wave w does nt=w&1, mt in {w>>1, (w>>1)+4}.
    {
      int nt = wv & 1, g2 = wv >> 1;
      int ncol = nt * 16 + m16;
      f16x8 bf[4];
#pragma unroll
      for (int t = 0; t < 4; ++t)
        bf[t] = ld_frag_g(W1s + ((l * 4 + t) * 32 + ncol) * 32 + q * 8);
      float b1v = b1[l * 32 + ncol];
#pragma unroll
      for (int mi = 0; mi < 2; ++mi) {
        int mt = g2 + mi * 4;
        if (mt < 6) {
          int e = mt * 16 + m16;
          int sn = srcn[e], dn = dstn[e];
          f32x4 acc = zero4;
#pragma unroll
          for (int t = 0; t < 4; ++t) {
            int nd = (t < 2) ? sn : dn;
            acc = MFMA16(ld_frag_s(&hH[nd][(t & 1) * 32 + q * 8]), bf[t], acc);
          }
#pragma unroll
          for (int t = 0; t < 4; ++t) {
            int nd = (t < 2) ? sn : dn;
            acc = MFMA16(ld_frag_s(&hL[nd][(t & 1) * 32 + q * 8]), bf[t], acc);
          }
#pragma unroll
          for (int r = 0; r < 4; ++r) {
            int e2 = mt * 16 + q * 4 + r;
            float v = fmaxf(acc[r] + b1v, 0.f);
            zT[ncol][e2] = (e2 < 82) ? v : 0.f;  // zero pad edges
          }
        }
      }
    }
    __syncthreads();

    // ---- msg GEMM: [96 x 2112] x [2112 x 64]
    // Wave w owns N-cols [(w&3)*16, +16); K-chunks split even/odd by par=w>>2.
    // Per chunk c (64 j's): S = (h_hi + h_lo)-frags x W2chunk, macc += z[e][c] * S.
    {
      f16x8 hAh[6][2], hAl[6][2];
#pragma unroll
      for (int mt = 0; mt < 6; ++mt) {
        int sn = srcn[mt * 16 + m16];
        hAh[mt][0] = ld_frag_s(&hH[sn][q * 8]);
        hAh[mt][1] = ld_frag_s(&hH[sn][32 + q * 8]);
        hAl[mt][0] = ld_frag_s(&hL[sn][q * 8]);
        hAl[mt][1] = ld_frag_s(&hL[sn][32 + q * 8]);
      }
      f32x4 macc[6];
#pragma unroll
      for (int mt = 0; mt < 6; ++mt) macc[mt] = zero4;

      int nt = wv & 3, par = wv >> 2;
      const _Float16* Wb = W2s + (size_t)l * 135168 + (nt * 16 + m16) * 32 + q * 8;
      f16x8 B0 = ld_frag_g(Wb + (size_t)(2 * par) * 2048);
      f16x8 B1 = ld_frag_g(Wb + (size_t)(2 * par + 1) * 2048);
      for (int c = par; c < 33; c += 2) {
        int cn = c + 2;
        f16x8 B0n, B1n;
        if (cn < 33) {
          B0n = ld_frag_g(Wb + (size_t)(2 * cn) * 2048);
          B1n = ld_frag_g(Wb + (size_t)(2 * cn + 1) * 2048);
        }
#pragma unroll
        for (int mt = 0; mt < 6; ++mt) {
          f32x4 S = MFMA16(hAh[mt][0], B0, zero4);
          S = MFMA16(hAh[mt][1], B1, S);
          S = MFMA16(hAl[mt][0], B0, S);
          S = MFMA16(hAl[mt][1], B1, S);
          f32x4 zf = *(const f32x4*)&zT[c][mt * 16 + q * 4];
          macc[mt] += zf * S;
        }
        B0 = B0n; B1 = B1n;
      }
      // scatter into agg (pad edges have z==0 for every chunk -> exact 0 contribution)
#pragma unroll
      for (int mt = 0; mt < 6; ++mt) {
#pragma unroll
        for (int r = 0; r < 4; ++r) {
          int e = mt * 16 + q * 4 + r;
          atomicAdd(&agg[dstn[e]][nt * 16 + m16], macc[mt][r]);
        }
      }
    }
    __syncthreads();

    // ---- epilogue: h = relu(BN(agg/deg + h@Wr + br)) + h
    // Wave w owns 16x16 tile: cols (w&3)*16.., rows (w>>2)*16..
    {
      int ncol = (wv & 3) * 16 + m16;
      int mt = wv >> 2;
      float scl = bns[l * 64 + ncol];
      float sft = bnh[l * 64 + ncol];
      float brb = brr[l * 64 + ncol];
      f16x8 wb0 = ld_frag_g(Wrs + ((l * 2 + 0) * 64 + ncol) * 32 + q * 8);
      f16x8 wb1 = ld_frag_g(Wrs + ((l * 2 + 1) * 64 + ncol) * 32 + q * 8);
      f32x4 acc = zero4;
      acc = MFMA16(ld_frag_s(&hH[mt * 16 + m16][q * 8]), wb0, acc);
      acc = MFMA16(ld_frag_s(&hH[mt * 16 + m16][32 + q * 8]), wb1, acc);
      acc = MFMA16(ld_frag_s(&hL[mt * 16 + m16][q * 8]), wb0, acc);
      acc = MFMA16(ld_frag_s(&hL[mt * 16 + m16][32 + q * 8]), wb1, acc);
      // all waves finish reading hH/hL (full K range) before any wave overwrites
      __syncthreads();
#pragma unroll
      for (int r = 0; r < 4; ++r) {
        int row = mt * 16 + q * 4 + r;
        if (row < 30) {
          float v = agg[row][ncol] * invdeg[row] + acc[r] + brb;
          v = v * scl + sft;
          float hn = fmaxf(v, 0.f) + hF[row][ncol];
          hF[row][ncol] = hn;
          _Float16 hi = (_Float16)hn;
          hH[row][ncol] = hi;
          hL[row][ncol] = (_Float16)(hn - (float)hi);
        }
      }
    }
    __syncthreads();
  }

  // ---- head: out = relu([h_u|h_v] @ Wm1 + bm1) @ Wm2 + bm2 (fp32, from hF)
  float* hid = (float*)zT;  // reuse as [c][i] (c*41 + i), 2624 <= 3300 floats
  for (int u = tid; u < 41 * 64; u += 512) {
    int i = u >> 6, c = u & 63;
    int ui = srcn[i], vi = dstn[i];
    float acc = bm1[c];
#pragma unroll 4
    for (int k = 0; k < 64; ++k)
      acc += hF[ui][k] * Wm1[k * 64 + c] + hF[vi][k] * Wm1[(64 + k) * 64 + c];
    hid[c * 41 + i] = fmaxf(acc, 0.f);
  }
  __syncthreads();
  if (tid < 41) {
    float acc = bm2[0];
    for (int c = 0; c < 64; ++c) acc += hid[c * 41 + tid] * Wm2[c];
    out[g * 41 + tid] = acc;
  }
}

extern "C" void kernel_launch(void* const* d_in, const int* in_sizes, int n_in,
                              void* d_out, int out_size, void* d_ws, size_t ws_size,
                              hipStream_t stream) {
  const float* x   = (const float*)d_in[0];
  // d_in[1] = edge_index (rebuilt from branch lists), d_in[4] = num_graphs (const 512)
  const int* bu    = (const int*)d_in[2];
  const int* bv    = (const int*)d_in[3];
  const float* Wp  = (const float*)d_in[5];
  const float* bp  = (const float*)d_in[6];
  const float* W1  = (const float*)d_in[7];
  const float* b1  = (const float*)d_in[8];
  const float* W2  = (const float*)d_in[9];
  const float* b2  = (const float*)d_in[10];
  const float* Wr  = (const float*)d_in[11];
  const float* br  = (const float*)d_in[12];
  const float* gm  = (const float*)d_in[13];
  const float* bt  = (const float*)d_in[14];
  const float* rm  = (const float*)d_in[15];
  const float* rv  = (const float*)d_in[16];
  const float* Wm1 = (const float*)d_in[17];
  const float* bm1 = (const float*)d_in[18];
  const float* Wm2 = (const float*)d_in[19];
  const float* bm2 = (const float*)d_in[20];
  unsigned char* ws = (unsigned char*)d_ws;
  float* out = (float*)d_out;

  // ws usage: 1436160 B (repacked f16 weights + folded BN params), rewritten every call
  prep_kernel<<<2802, 256, 0, stream>>>(W1, W2, b2, Wr, gm, bt, rm, rv, ws);
  gnn_kernel<<<512, 512, 0, stream>>>(
      x, bu, bv, Wp, bp, b1, br, Wm1, bm1, Wm2, bm2,
      (const _Float16*)(ws + WS_W2S),
      (const _Float16*)(ws + WS_W1S),
      (const _Float16*)(ws + WS_WRS),
      (const float*)(ws + WS_BNS),
      (const float*)(ws + WS_BNH),
      out);
}

// Round 4
// 278.521 us; speedup vs baseline: 2.0860x; 2.0860x over previous
//
#include <hip/hip_runtime.h>

// ECGNNEdgePredictor: 512 graphs x 30 nodes, HID=64, 5 NNConv layers + MLP head.
// One block per graph, 512 threads = 8 waves (16 waves/CU at 2 blocks/CU).
// R3 post-mortem: K-split msg GEMM kept 6 M-tiles of A-frags per wave -> 160+ VGPRs
// -> spills (WRITE_SIZE 363 MB). R4: M-split across wave pairs (3 M-tiles/wave,
// ~100 VGPRs) — same MFMA count, fits in the 128-VGPR budget for 4 waves/SIMD.
// msg GEMM fused as P @ W2' with P[e,k*64+h] = z[e,k]*h_src[e,h] (+ones col for b2);
// z-scale (fp32) folded into the accumulator. fp16 MFMA with A-operand hi/lo split.

typedef float f32x4 __attribute__((ext_vector_type(4)));
typedef _Float16 f16x8 __attribute__((ext_vector_type(8)));

#define MFMA16(a, b, c) __builtin_amdgcn_mfma_f32_16x16x32_f16((a), (b), (c), 0, 0, 0)

// ws layout (bytes)
#define WS_W2S 0u        // 5*66*64*32 f16 = 1351680 B (W2 + b2 fused, B-frag order)
#define WS_W1S 1351680u  // 5*4*32*32  f16 = 40960 B
#define WS_WRS 1392640u  // 5*2*64*32  f16 = 40960 B
#define WS_BNS 1433600u  // 320 f32 scale
#define WS_BNH 1434880u  // 320 f32 shift
// total 1436160 B

__device__ inline f16x8 ld_frag_g(const _Float16* p) {
  union { uint4 u; f16x8 f; } c;
  c.u = *(const uint4*)p;
  return c.f;
}
__device__ inline f16x8 ld_frag_s(const _Float16* p) { return *(const f16x8*)p; }

// ---------------- prep: repack weights to f16 in MFMA B-fragment order ----------------
// B-frag layout per 16x16x32 k-step t: elem(t, n, q, i) = B[j = t*32 + q*8 + i][n],
// stored contiguous in (q,i) so lane (col n, q=lane>>4) loads 16B.
__global__ __launch_bounds__(256) void prep_kernel(
    const float* __restrict__ W1, const float* __restrict__ W2,
    const float* __restrict__ b2, const float* __restrict__ Wr,
    const float* __restrict__ gamma, const float* __restrict__ beta,
    const float* __restrict__ rmean, const float* __restrict__ rvar,
    unsigned char* __restrict__ ws) {
  int idx = blockIdx.x * 256 + threadIdx.x;
  _Float16* W2s = (_Float16*)(ws + WS_W2S);
  _Float16* W1s = (_Float16*)(ws + WS_W1S);
  _Float16* Wrs = (_Float16*)(ws + WS_WRS);
  float* bns = (float*)(ws + WS_BNS);
  float* bnh = (float*)(ws + WS_BNH);

  if (idx < 675840) {            // W2s: K = 2112 = 32*64 (z x h outer) + 64 (b2 rows)
    int l = idx / 135168, r = idx % 135168;
    int t = r / 2048, r2 = r % 2048;
    int n = r2 >> 5, s = r2 & 31;
    int j = t * 32 + s;
    float v = (j < 2048) ? W2[(l * 32 + (j >> 6)) * 4096 + (j & 63) * 64 + n]
                         : b2[l * 4096 + (j - 2048) * 64 + n];
    W2s[idx] = (_Float16)v;
  } else if (idx < 696320) {     // W1s: K = 128
    int i2 = idx - 675840;
    int l = i2 / 4096, r = i2 % 4096;
    int t = r >> 10, n = (r >> 5) & 31, s = r & 31;
    int j = t * 32 + s;
    W1s[i2] = (_Float16)W1[l * 4096 + j * 32 + n];
  } else if (idx < 716800) {     // Wrs: K = 64
    int i3 = idx - 696320;
    int l = i3 / 4096, r = i3 % 4096;
    int t = r >> 11, rem = r & 2047;
    int n = rem >> 5, s = rem & 31;
    int j = t * 32 + s;
    Wrs[i3] = (_Float16)Wr[l * 4096 + j * 64 + n];
  } else if (idx < 717120) {     // BN folded: scale, shift
    int i4 = idx - 716800;       // l*64 + c
    float sc = gamma[i4] * rsqrtf(rvar[i4] + 1e-5f);
    bns[i4] = sc;
    bnh[i4] = beta[i4] - rmean[i4] * sc;
  }
}

// ---------------- main: one block per graph, 512 threads = 8 waves ----------------
__global__ __launch_bounds__(512, 4) void gnn_kernel(
    const float* __restrict__ x, const int* __restrict__ bu, const int* __restrict__ bv,
    const float* __restrict__ Wp, const float* __restrict__ bp,
    const float* __restrict__ b1, const float* __restrict__ brr,
    const float* __restrict__ Wm1, const float* __restrict__ bm1,
    const float* __restrict__ Wm2, const float* __restrict__ bm2,
    const _Float16* __restrict__ W2s, const _Float16* __restrict__ W1s,
    const _Float16* __restrict__ Wrs,
    const float* __restrict__ bns, const float* __restrict__ bnh,
    float* __restrict__ out) {
  __shared__ __align__(16) float hF[32][68];         // fp32 master h
  __shared__ __align__(16) _Float16 hH[32][72];      // f16 hi part of h
  __shared__ __align__(16) _Float16 hL[32][72];      // f16 lo part (h - hi)
  __shared__ __align__(16) float zT[33][100];        // z transposed [c][e]; row 32 = ones
  __shared__ __align__(16) float agg[32][68];        // scatter accumulator
  __shared__ int srcn[96], dstn[96];
  __shared__ float invdeg[32];

  const int tid = threadIdx.x;
  const int g = blockIdx.x;
  const int wv = tid >> 6;     // 0..7
  const int ln = tid & 63;
  const int q = ln >> 4;
  const int m16 = ln & 15;

  // ---- init: edge lists (both directions), ones-column, pad rows
  if (tid < 96) {
    int s, d;
    if (tid < 41)      { s = bu[tid];      d = bv[tid]; }
    else if (tid < 82) { s = bv[tid - 41]; d = bu[tid - 41]; }
    else               { s = 0;            d = 0; }
    srcn[tid] = s; dstn[tid] = d;
    zT[32][tid] = (tid < 82) ? 1.0f : 0.0f;
  }
  if (tid < 136) { hF[30 + tid / 68][tid % 68] = 0.f; }
  if (tid < 144) {
    hH[30 + tid / 72][tid % 72] = (_Float16)0.f;
    hL[30 + tid / 72][tid % 72] = (_Float16)0.f;
  }
  __syncthreads();
  if (tid < 32) {
    int cnt = 0;
    for (int e = 0; e < 82; ++e) cnt += (dstn[e] == tid) ? 1 : 0;
    invdeg[tid] = 1.0f / (float)(cnt > 0 ? cnt : 1);
  }
  // ---- projection h0 = x @ Wp + bp (fp32, then split hi/lo)
  for (int u = tid; u < 30 * 64; u += 512) {
    int n = u >> 6, c = u & 63;
    float acc = bp[c];
#pragma unroll
    for (int k = 0; k < 8; ++k) acc += x[(g * 30 + n) * 8 + k] * Wp[k * 64 + c];
    hF[n][c] = acc;
    _Float16 hi = (_Float16)acc;
    hH[n][c] = hi;
    hL[n][c] = (_Float16)(acc - (float)hi);
  }
  __syncthreads();

  const f32x4 zero4 = {0.f, 0.f, 0.f, 0.f};

  for (int l = 0; l < 5; ++l) {
    // zero scatter buffer (atomics start only after the post-z barrier)
    for (int u = tid; u < 32 * 68; u += 512) ((float*)agg)[u] = 0.f;

    // ---- z = relu([h_src|h_dst] @ W1 + b1): M=96 N=32 K=128 -> zT[c][e] (fp32)
    // 12 tiles (6 mt x 2 nt) over 8 waves: wave w does nt=w&1, mt in {w>>1, (w>>1)+4}.
    {
      int nt = wv & 1, g2 = wv >> 1;
      int ncol = nt * 16 + m16;
      f16x8 bf[4];
#pragma unroll
      for (int t = 0; t < 4; ++t)
        bf[t] = ld_frag_g(W1s + ((l * 4 + t) * 32 + ncol) * 32 + q * 8);
      float b1v = b1[l * 32 + ncol];
#pragma unroll
      for (int mi = 0; mi < 2; ++mi) {
        int mt = g2 + mi * 4;
        if (mt < 6) {
          int e = mt * 16 + m16;
          int sn = srcn[e], dn = dstn[e];
          f32x4 acc = zero4;
#pragma unroll
          for (int t = 0; t < 4; ++t) {
            int nd = (t < 2) ? sn : dn;
            acc = MFMA16(ld_frag_s(&hH[nd][(t & 1) * 32 + q * 8]), bf[t], acc);
          }
#pragma unroll
          for (int t = 0; t < 4; ++t) {
            int nd = (t < 2) ? sn : dn;
            acc = MFMA16(ld_frag_s(&hL[nd][(t & 1) * 32 + q * 8]), bf[t], acc);
          }
#pragma unroll
          for (int r = 0; r < 4; ++r) {
            int e2 = mt * 16 + q * 4 + r;
            float v = fmaxf(acc[r] + b1v, 0.f);
            zT[ncol][e2] = (e2 < 82) ? v : 0.f;  // zero pad edges
          }
        }
      }
    }
    __syncthreads();

    // ---- msg GEMM: [96 x 2112] x [2112 x 64]
    // Wave w owns N-cols [(w&3)*16, +16) and M-half (w>>2): edge tiles mh*3..mh*3+2.
    // Each wave streams ALL 33 K-chunks (A-frag state: 3 tiles -> ~100 VGPR, no spill).
    // Per chunk c: S = (h_hi + h_lo)-frags x W2chunk, macc += z[e][c] * S.
    {
      int nt = wv & 3, mh = wv >> 2;
      f16x8 hAh[3][2], hAl[3][2];
#pragma unroll
      for (int mi = 0; mi < 3; ++mi) {
        int sn = srcn[(mh * 3 + mi) * 16 + m16];
        hAh[mi][0] = ld_frag_s(&hH[sn][q * 8]);
        hAh[mi][1] = ld_frag_s(&hH[sn][32 + q * 8]);
        hAl[mi][0] = ld_frag_s(&hL[sn][q * 8]);
        hAl[mi][1] = ld_frag_s(&hL[sn][32 + q * 8]);
      }
      f32x4 macc[3];
#pragma unroll
      for (int mi = 0; mi < 3; ++mi) macc[mi] = zero4;

      const _Float16* Wb = W2s + (size_t)l * 135168 + (nt * 16 + m16) * 32 + q * 8;
      f16x8 B0 = ld_frag_g(Wb);
      f16x8 B1 = ld_frag_g(Wb + 2048);
      for (int c = 0; c < 33; ++c) {
        f16x8 B0n, B1n;
        if (c < 32) {
          B0n = ld_frag_g(Wb + (size_t)(2 * c + 2) * 2048);
          B1n = ld_frag_g(Wb + (size_t)(2 * c + 3) * 2048);
        }
#pragma unroll
        for (int mi = 0; mi < 3; ++mi) {
          f32x4 S = MFMA16(hAh[mi][0], B0, zero4);
          S = MFMA16(hAh[mi][1], B1, S);
          S = MFMA16(hAl[mi][0], B0, S);
          S = MFMA16(hAl[mi][1], B1, S);
          f32x4 zf = *(const f32x4*)&zT[c][(mh * 3 + mi) * 16 + q * 4];
          macc[mi] += zf * S;
        }
        B0 = B0n; B1 = B1n;
      }
      // scatter into agg (pad edges have z==0 for every chunk -> exact 0 contribution)
#pragma unroll
      for (int mi = 0; mi < 3; ++mi) {
#pragma unroll
        for (int r = 0; r < 4; ++r) {
          int e = (mh * 3 + mi) * 16 + q * 4 + r;
          atomicAdd(&agg[dstn[e]][nt * 16 + m16], macc[mi][r]);
        }
      }
    }
    __syncthreads();

    // ---- epilogue: h = relu(BN(agg/deg + h@Wr + br)) + h
    // Wave w owns 16x16 tile: cols (w&3)*16.., rows (w>>2)*16..
    {
      int ncol = (wv & 3) * 16 + m16;
      int mt = wv >> 2;
      float scl = bns[l * 64 + ncol];
      float sft = bnh[l * 64 + ncol];
      float brb = brr[l * 64 + ncol];
      f16x8 wb0 = ld_frag_g(Wrs + ((l * 2 + 0) * 64 + ncol) * 32 + q * 8);
      f16x8 wb1 = ld_frag_g(Wrs + ((l * 2 + 1) * 64 + ncol) * 32 + q * 8);
      f32x4 acc = zero4;
      acc = MFMA16(ld_frag_s(&hH[mt * 16 + m16][q * 8]), wb0, acc);
      acc = MFMA16(ld_frag_s(&hH[mt * 16 + m16][32 + q * 8]), wb1, acc);
      acc = MFMA16(ld_frag_s(&hL[mt * 16 + m16][q * 8]), wb0, acc);
      acc = MFMA16(ld_frag_s(&hL[mt * 16 + m16][32 + q * 8]), wb1, acc);
      // all waves finish reading hH/hL (full K range) before any wave overwrites
      __syncthreads();
#pragma unroll
      for (int r = 0; r < 4; ++r) {
        int row = mt * 16 + q * 4 + r;
        if (row < 30) {
          float v = agg[row][ncol] * invdeg[row] + acc[r] + brb;
          v = v * scl + sft;
          float hn = fmaxf(v, 0.f) + hF[row][ncol];
          hF[row][ncol] = hn;
          _Float16 hi = (_Float16)hn;
          hH[row][ncol] = hi;
          hL[row][ncol] = (_Float16)(hn - (float)hi);
        }
      }
    }
    __syncthreads();
  }

  // ---- head: out = relu([h_u|h_v] @ Wm1 + bm1) @ Wm2 + bm2 (fp32, from hF)
  float* hid = (float*)zT;  // reuse as [c][i] (c*41 + i), 2624 <= 3300 floats
  for (int u = tid; u < 41 * 64; u += 512) {
    int i = u >> 6, c = u & 63;
    int ui = srcn[i], vi = dstn[i];
    float acc = bm1[c];
#pragma unroll 4
    for (int k = 0; k < 64; ++k)
      acc += hF[ui][k] * Wm1[k * 64 + c] + hF[vi][k] * Wm1[(64 + k) * 64 + c];
    hid[c * 41 + i] = fmaxf(acc, 0.f);
  }
  __syncthreads();
  if (tid < 41) {
    float acc = bm2[0];
    for (int c = 0; c < 64; ++c) acc += hid[c * 41 + tid] * Wm2[c];
    out[g * 41 + tid] = acc;
  }
}

extern "C" void kernel_launch(void* const* d_in, const int* in_sizes, int n_in,
                              void* d_out, int out_size, void* d_ws, size_t ws_size,
                              hipStream_t stream) {
  const float* x   = (const float*)d_in[0];
  // d_in[1] = edge_index (rebuilt from branch lists), d_in[4] = num_graphs (const 512)
  const int* bu    = (const int*)d_in[2];
  const int* bv    = (const int*)d_in[3];
  const float* Wp  = (const float*)d_in[5];
  const float* bp  = (const float*)d_in[6];
  const float* W1  = (const float*)d_in[7];
  const float* b1  = (const float*)d_in[8];
  const float* W2  = (const float*)d_in[9];
  const float* b2  = (const float*)d_in[10];
  const float* Wr  = (const float*)d_in[11];
  const float* br  = (const float*)d_in[12];
  const float* gm  = (const float*)d_in[13];
  const float* bt  = (const float*)d_in[14];
  const float* rm  = (const float*)d_in[15];
  const float* rv  = (const float*)d_in[16];
  const float* Wm1 = (const float*)d_in[17];
  const float* bm1 = (const float*)d_in[18];
  const float* Wm2 = (const float*)d_in[19];
  const float* bm2 = (const float*)d_in[20];
  unsigned char* ws = (unsigned char*)d_ws;
  float* out = (float*)d_out;

  // ws usage: 1436160 B (repacked f16 weights + folded BN params), rewritten every call
  prep_kernel<<<2802, 256, 0, stream>>>(W1, W2, b2, Wr, gm, bt, rm, rv, ws);
  gnn_kernel<<<512, 512, 0, stream>>>(
      x, bu, bv, Wp, bp, b1, br, Wm1, bm1, Wm2, bm2,
      (const _Float16*)(ws + WS_W2S),
      (const _Float16*)(ws + WS_W1S),
      (const _Float16*)(ws + WS_WRS),
      (const float*)(ws + WS_BNS),
      (const float*)(ws + WS_BNH),
      out);
}

// Round 5
// 272.736 us; speedup vs baseline: 2.1303x; 1.0212x over previous
//
#include <hip/hip_runtime.h>

// ECGNNEdgePredictor: 512 graphs x 30 nodes, HID=64, 5 NNConv layers + MLP head.
// One block per graph, 512 threads = 8 waves (16 waves/CU at 2 blocks/CU).
// R4 post-mortem: msg loop's macc += zf*S forced an MFMA->VALU join per chunk;
// waves are barrier-lockstepped so the stalls align -> MfmaUtil stuck at 29%.
// R5: fold z into the A-operand (A' = f16(z) (*) hA, v_pk_mul_f16) so the msg loop
// is pure MFMA->MFMA C-accumulation; drop hi/lo in msg (halves msg MFMAs; z is
// f16-rounded in A' anyway). B prefetch depth 2, register-pipelined z reads.
// z-GEMM and root epilogue keep the hi/lo split (cheap, 2% of MFMAs).

typedef float f32x4 __attribute__((ext_vector_type(4)));
typedef _Float16 f16x8 __attribute__((ext_vector_type(8)));

#define MFMA16(a, b, c) __builtin_amdgcn_mfma_f32_16x16x32_f16((a), (b), (c), 0, 0, 0)

// ws layout (bytes)
#define WS_W2S 0u        // 5*66*64*32 f16 = 1351680 B (W2 + b2 fused, B-frag order)
#define WS_W1S 1351680u  // 5*4*32*32  f16 = 40960 B
#define WS_WRS 1392640u  // 5*2*64*32  f16 = 40960 B
#define WS_BNS 1433600u  // 320 f32 scale
#define WS_BNH 1434880u  // 320 f32 shift
// total 1436160 B

__device__ inline f16x8 ld_frag_g(const _Float16* p) {
  union { uint4 u; f16x8 f; } c;
  c.u = *(const uint4*)p;
  return c.f;
}
__device__ inline f16x8 ld_frag_s(const _Float16* p) { return *(const f16x8*)p; }

// ---------------- prep: repack weights to f16 in MFMA B-fragment order ----------------
// B-frag layout per 16x16x32 k-step t: elem(t, n, q, i) = B[j = t*32 + q*8 + i][n],
// stored contiguous in (q,i) so lane (col n, q=lane>>4) loads 16B.
__global__ __launch_bounds__(256) void prep_kernel(
    const float* __restrict__ W1, const float* __restrict__ W2,
    const float* __restrict__ b2, const float* __restrict__ Wr,
    const float* __restrict__ gamma, const float* __restrict__ beta,
    const float* __restrict__ rmean, const float* __restrict__ rvar,
    unsigned char* __restrict__ ws) {
  int idx = blockIdx.x * 256 + threadIdx.x;
  _Float16* W2s = (_Float16*)(ws + WS_W2S);
  _Float16* W1s = (_Float16*)(ws + WS_W1S);
  _Float16* Wrs = (_Float16*)(ws + WS_WRS);
  float* bns = (float*)(ws + WS_BNS);
  float* bnh = (float*)(ws + WS_BNH);

  if (idx < 675840) {            // W2s: K = 2112 = 32*64 (z x h outer) + 64 (b2 rows)
    int l = idx / 135168, r = idx % 135168;
    int t = r / 2048, r2 = r % 2048;
    int n = r2 >> 5, s = r2 & 31;
    int j = t * 32 + s;
    float v = (j < 2048) ? W2[(l * 32 + (j >> 6)) * 4096 + (j & 63) * 64 + n]
                         : b2[l * 4096 + (j - 2048) * 64 + n];
    W2s[idx] = (_Float16)v;
  } else if (idx < 696320) {     // W1s: K = 128
    int i2 = idx - 675840;
    int l = i2 / 4096, r = i2 % 4096;
    int t = r >> 10, n = (r >> 5) & 31, s = r & 31;
    int j = t * 32 + s;
    W1s[i2] = (_Float16)W1[l * 4096 + j * 32 + n];
  } else if (idx < 716800) {     // Wrs: K = 64
    int i3 = idx - 696320;
    int l = i3 / 4096, r = i3 % 4096;
    int t = r >> 11, rem = r & 2047;
    int n = rem >> 5, s = rem & 31;
    int j = t * 32 + s;
    Wrs[i3] = (_Float16)Wr[l * 4096 + j * 64 + n];
  } else if (idx < 717120) {     // BN folded: scale, shift
    int i4 = idx - 716800;       // l*64 + c
    float sc = gamma[i4] * rsqrtf(rvar[i4] + 1e-5f);
    bns[i4] = sc;
    bnh[i4] = beta[i4] - rmean[i4] * sc;
  }
}

// ---------------- main: one block per graph, 512 threads = 8 waves ----------------
__global__ __launch_bounds__(512, 4) void gnn_kernel(
    const float* __restrict__ x, const int* __restrict__ bu, const int* __restrict__ bv,
    const float* __restrict__ Wp, const float* __restrict__ bp,
    const float* __restrict__ b1, const float* __restrict__ brr,
    const float* __restrict__ Wm1, const float* __restrict__ bm1,
    const float* __restrict__ Wm2, const float* __restrict__ bm2,
    const _Float16* __restrict__ W2s, const _Float16* __restrict__ W1s,
    const _Float16* __restrict__ Wrs,
    const float* __restrict__ bns, const float* __restrict__ bnh,
    float* __restrict__ out) {
  __shared__ __align__(16) float hF[32][68];         // fp32 master h
  __shared__ __align__(16) _Float16 hH[32][72];      // f16 hi part of h
  __shared__ __align__(16) _Float16 hL[32][72];      // f16 lo part (h - hi)
  __shared__ __align__(16) float zT[33][100];        // z transposed [c][e]; row 32 = ones
  __shared__ __align__(16) float agg[32][68];        // scatter accumulator
  __shared__ int srcn[96], dstn[96];
  __shared__ float invdeg[32];

  const int tid = threadIdx.x;
  const int g = blockIdx.x;
  const int wv = tid >> 6;     // 0..7
  const int ln = tid & 63;
  const int q = ln >> 4;
  const int m16 = ln & 15;

  // ---- init: edge lists (both directions), ones-column, pad rows
  if (tid < 96) {
    int s, d;
    if (tid < 41)      { s = bu[tid];      d = bv[tid]; }
    else if (tid < 82) { s = bv[tid - 41]; d = bu[tid - 41]; }
    else               { s = 0;            d = 0; }
    srcn[tid] = s; dstn[tid] = d;
    zT[32][tid] = (tid < 82) ? 1.0f : 0.0f;
  }
  if (tid < 136) { hF[30 + tid / 68][tid % 68] = 0.f; }
  if (tid < 144) {
    hH[30 + tid / 72][tid % 72] = (_Float16)0.f;
    hL[30 + tid / 72][tid % 72] = (_Float16)0.f;
  }
  __syncthreads();
  if (tid < 32) {
    int cnt = 0;
    for (int e = 0; e < 82; ++e) cnt += (dstn[e] == tid) ? 1 : 0;
    invdeg[tid] = 1.0f / (float)(cnt > 0 ? cnt : 1);
  }
  // ---- projection h0 = x @ Wp + bp (fp32, then split hi/lo)
  for (int u = tid; u < 30 * 64; u += 512) {
    int n = u >> 6, c = u & 63;
    float acc = bp[c];
#pragma unroll
    for (int k = 0; k < 8; ++k) acc += x[(g * 30 + n) * 8 + k] * Wp[k * 64 + c];
    hF[n][c] = acc;
    _Float16 hi = (_Float16)acc;
    hH[n][c] = hi;
    hL[n][c] = (_Float16)(acc - (float)hi);
  }
  __syncthreads();

  const f32x4 zero4 = {0.f, 0.f, 0.f, 0.f};

  for (int l = 0; l < 5; ++l) {
    // zero scatter buffer (atomics start only after the post-z barrier)
    for (int u = tid; u < 32 * 68; u += 512) ((float*)agg)[u] = 0.f;

    // ---- z = relu([h_src|h_dst] @ W1 + b1): M=96 N=32 K=128 -> zT[c][e] (fp32)
    // 12 tiles (6 mt x 2 nt) over 8 waves: wave w does nt=w&1, mt in {w>>1, (w>>1)+4}.
    {
      int nt = wv & 1, g2 = wv >> 1;
      int ncol = nt * 16 + m16;
      f16x8 bf[4];
#pragma unroll
      for (int t = 0; t < 4; ++t)
        bf[t] = ld_frag_g(W1s + ((l * 4 + t) * 32 + ncol) * 32 + q * 8);
      float b1v = b1[l * 32 + ncol];
#pragma unroll
      for (int mi = 0; mi < 2; ++mi) {
        int mt = g2 + mi * 4;
        if (mt < 6) {
          int e = mt * 16 + m16;
          int sn = srcn[e], dn = dstn[e];
          f32x4 acc = zero4;
#pragma unroll
          for (int t = 0; t < 4; ++t) {
            int nd = (t < 2) ? sn : dn;
            acc = MFMA16(ld_frag_s(&hH[nd][(t & 1) * 32 + q * 8]), bf[t], acc);
          }
#pragma unroll
          for (int t = 0; t < 4; ++t) {
            int nd = (t < 2) ? sn : dn;
            acc = MFMA16(ld_frag_s(&hL[nd][(t & 1) * 32 + q * 8]), bf[t], acc);
          }
#pragma unroll
          for (int r = 0; r < 4; ++r) {
            int e2 = mt * 16 + q * 4 + r;
            float v = fmaxf(acc[r] + b1v, 0.f);
            zT[ncol][e2] = (e2 < 82) ? v : 0.f;  // zero pad edges
          }
        }
      }
    }
    __syncthreads();

    // ---- msg GEMM: [96 x 2112] x [2112 x 64]
    // Wave w owns N-cols [(w&3)*16, +16) and M-half (w>>2): edge tiles mh*3..mh*3+2.
    // z folded into the A-operand: macc[mi] = MFMA(f16(z) * hA, B, macc[mi]) —
    // pure MFMA->MFMA accumulation, no MFMA-result reads inside the loop.
    {
      int nt = wv & 3, mh = wv >> 2;
      int e0 = (mh * 3 + 0) * 16 + m16;
      int e1 = (mh * 3 + 1) * 16 + m16;
      int e2 = (mh * 3 + 2) * 16 + m16;
      f16x8 hA[3][2];
      {
        int s0 = srcn[e0], s1 = srcn[e1], s2 = srcn[e2];
        hA[0][0] = ld_frag_s(&hH[s0][q * 8]);
        hA[0][1] = ld_frag_s(&hH[s0][32 + q * 8]);
        hA[1][0] = ld_frag_s(&hH[s1][q * 8]);
        hA[1][1] = ld_frag_s(&hH[s1][32 + q * 8]);
        hA[2][0] = ld_frag_s(&hH[s2][q * 8]);
        hA[2][1] = ld_frag_s(&hH[s2][32 + q * 8]);
      }
      f32x4 macc[3];
#pragma unroll
      for (int mi = 0; mi < 3; ++mi) macc[mi] = zero4;

      const _Float16* Wb = W2s + (size_t)l * 135168 + (nt * 16 + m16) * 32 + q * 8;
      // 2-deep B software pipeline + 1-deep z pipeline
      f16x8 Ba0 = ld_frag_g(Wb + 0 * 2048);
      f16x8 Ba1 = ld_frag_g(Wb + 1 * 2048);
      f16x8 Bb0 = ld_frag_g(Wb + 2 * 2048);
      f16x8 Bb1 = ld_frag_g(Wb + 3 * 2048);
      float zc0 = zT[0][e0], zc1 = zT[0][e1], zc2 = zT[0][e2];
      for (int c = 0; c < 33; ++c) {
        f16x8 Bn0, Bn1;
        if (c + 2 < 33) {
          Bn0 = ld_frag_g(Wb + (size_t)(2 * c + 4) * 2048);
          Bn1 = ld_frag_g(Wb + (size_t)(2 * c + 5) * 2048);
        }
        float zn0, zn1, zn2;
        if (c + 1 < 33) {
          zn0 = zT[c + 1][e0]; zn1 = zT[c + 1][e1]; zn2 = zT[c + 1][e2];
        }
        _Float16 z0 = (_Float16)zc0, z1 = (_Float16)zc1, z2 = (_Float16)zc2;
        macc[0] = MFMA16(hA[0][0] * z0, Ba0, macc[0]);
        macc[0] = MFMA16(hA[0][1] * z0, Ba1, macc[0]);
        macc[1] = MFMA16(hA[1][0] * z1, Ba0, macc[1]);
        macc[1] = MFMA16(hA[1][1] * z1, Ba1, macc[1]);
        macc[2] = MFMA16(hA[2][0] * z2, Ba0, macc[2]);
        macc[2] = MFMA16(hA[2][1] * z2, Ba1, macc[2]);
        Ba0 = Bb0; Ba1 = Bb1; Bb0 = Bn0; Bb1 = Bn1;
        zc0 = zn0; zc1 = zn1; zc2 = zn2;
      }
      // scatter into agg (pad edges have z==0 for every chunk -> exact 0 contribution)
#pragma unroll
      for (int mi = 0; mi < 3; ++mi) {
#pragma unroll
        for (int r = 0; r < 4; ++r) {
          int e = (mh * 3 + mi) * 16 + q * 4 + r;
          atomicAdd(&agg[dstn[e]][nt * 16 + m16], macc[mi][r]);
        }
      }
    }
    __syncthreads();

    // ---- epilogue: h = relu(BN(agg/deg + h@Wr + br)) + h
    // Wave w owns 16x16 tile: cols (w&3)*16.., rows (w>>2)*16..
    {
      int ncol = (wv & 3) * 16 + m16;
      int mt = wv >> 2;
      float scl = bns[l * 64 + ncol];
      float sft = bnh[l * 64 + ncol];
      float brb = brr[l * 64 + ncol];
      f16x8 wb0 = ld_frag_g(Wrs + ((l * 2 + 0) * 64 + ncol) * 32 + q * 8);
      f16x8 wb1 = ld_frag_g(Wrs + ((l * 2 + 1) * 64 + ncol) * 32 + q * 8);
      f32x4 acc = zero4;
      acc = MFMA16(ld_frag_s(&hH[mt * 16 + m16][q * 8]), wb0, acc);
      acc = MFMA16(ld_frag_s(&hH[mt * 16 + m16][32 + q * 8]), wb1, acc);
      acc = MFMA16(ld_frag_s(&hL[mt * 16 + m16][q * 8]), wb0, acc);
      acc = MFMA16(ld_frag_s(&hL[mt * 16 + m16][32 + q * 8]), wb1, acc);
      // all waves finish reading hH/hL (full K range) before any wave overwrites
      __syncthreads();
#pragma unroll
      for (int r = 0; r < 4; ++r) {
        int row = mt * 16 + q * 4 + r;
        if (row < 30) {
          float v = agg[row][ncol] * invdeg[row] + acc[r] + brb;
          v = v * scl + sft;
          float hn = fmaxf(v, 0.f) + hF[row][ncol];
          hF[row][ncol] = hn;
          _Float16 hi = (_Float16)hn;
          hH[row][ncol] = hi;
          hL[row][ncol] = (_Float16)(hn - (float)hi);
        }
      }
    }
    __syncthreads();
  }

  // ---- head: out = relu([h_u|h_v] @ Wm1 + bm1) @ Wm2 + bm2 (fp32, from hF)
  float* hid = (float*)zT;  // reuse as [c][i] (c*41 + i), 2624 <= 3300 floats
  for (int u = tid; u < 41 * 64; u += 512) {
    int i = u >> 6, c = u & 63;
    int ui = srcn[i], vi = dstn[i];
    float acc = bm1[c];
#pragma unroll 4
    for (int k = 0; k < 64; ++k)
      acc += hF[ui][k] * Wm1[k * 64 + c] + hF[vi][k] * Wm1[(64 + k) * 64 + c];
    hid[c * 41 + i] = fmaxf(acc, 0.f);
  }
  __syncthreads();
  if (tid < 41) {
    float acc = bm2[0];
    for (int c = 0; c < 64; ++c) acc += hid[c * 41 + tid] * Wm2[c];
    out[g * 41 + tid] = acc;
  }
}

extern "C" void kernel_launch(void* const* d_in, const int* in_sizes, int n_in,
                              void* d_out, int out_size, void* d_ws, size_t ws_size,
                              hipStream_t stream) {
  const float* x   = (const float*)d_in[0];
  // d_in[1] = edge_index (rebuilt from branch lists), d_in[4] = num_graphs (const 512)
  const int* bu    = (const int*)d_in[2];
  const int* bv    = (const int*)d_in[3];
  const float* Wp  = (const float*)d_in[5];
  const float* bp  = (const float*)d_in[6];
  const float* W1  = (const float*)d_in[7];
  const float* b1  = (const float*)d_in[8];
  const float* W2  = (const float*)d_in[9];
  const float* b2  = (const float*)d_in[10];
  const float* Wr  = (const float*)d_in[11];
  const float* br  = (const float*)d_in[12];
  const float* gm  = (const float*)d_in[13];
  const float* bt  = (const float*)d_in[14];
  const float* rm  = (const float*)d_in[15];
  const float* rv  = (const float*)d_in[16];
  const float* Wm1 = (const float*)d_in[17];
  const float* bm1 = (const float*)d_in[18];
  const float* Wm2 = (const float*)d_in[19];
  const float* bm2 = (const float*)d_in[20];
  unsigned char* ws = (unsigned char*)d_ws;
  float* out = (float*)d_out;

  // ws usage: 1436160 B (repacked f16 weights + folded BN params), rewritten every call
  prep_kernel<<<2802, 256, 0, stream>>>(W1, W2, b2, Wr, gm, bt, rm, rv, ws);
  gnn_kernel<<<512, 512, 0, stream>>>(
      x, bu, bv, Wp, bp, b1, br, Wm1, bm1, Wm2, bm2,
      (const _Float16*)(ws + WS_W2S),
      (const _Float16*)(ws + WS_W1S),
      (const _Float16*)(ws + WS_WRS),
      (const float*)(ws + WS_BNS),
      (const float*)(ws + WS_BNH),
      out);
}